// Round 1
// baseline (9996.152 us; speedup 1.0000x reference)
//
#include <hip/hip_runtime.h>
#include <hip/hip_bf16.h>

// LSTM decoder: B=512, H=1024, NCHAR=128, T=256.
// Strategy: single persistent kernel (256 blocks = 1/CU), grid barrier per step.
//  - fused W' = W_ih[:,128:] + W_hh  (bf16, permuted rows) resident in LDS per block
//  - x_part precomputed fp32, held in registers as MFMA acc init
//  - cell state c in registers for all 256 steps
//  - h double-buffered bf16 in workspace (the only cross-block state)
//  - out GEMM (h@W_out^T) folded in: 16x16 tile per block, buffered 16 steps in LDS

using bf16 = __hip_bfloat16;
typedef short bf16x8 __attribute__((ext_vector_type(8)));
typedef float f32x4  __attribute__((ext_vector_type(4)));
typedef float f32x16 __attribute__((ext_vector_type(16)));

static constexpr int BATCH = 512;
static constexpr int HID   = 1024;
static constexpr int NCH   = 128;
static constexpr int TLEN  = 256;
static constexpr int NP    = 4096;   // 4*HID

// workspace byte offsets
static constexpr size_t OFF_WP  = 0;                                // bf16 [4096][1024] fused W, rows permuted
static constexpr size_t OFF_WOB = OFF_WP  + (size_t)NP * HID * 2;   // bf16 [128][1024]
static constexpr size_t OFF_HB0 = OFF_WOB + (size_t)NCH * HID * 2;  // bf16 h buffer 0
static constexpr size_t OFF_HB1 = OFF_HB0 + (size_t)BATCH * HID * 2;
static constexpr size_t OFF_XP  = OFF_HB1 + (size_t)BATCH * HID * 2; // f32 [512][4096] x_part permuted
static constexpr size_t OFF_BAR = OFF_XP  + (size_t)BATCH * NP * 4;  // barrier counters (8 x 64B)
// total ~19.2 MB

__device__ __forceinline__ float sigm(float x) { return 1.f / (1.f + __expf(-x)); }

// permuted gate-row index: row' = (j>>4)*64 + gate*16 + (j&15); decode n = gate*H + j
__device__ __forceinline__ int rowp_to_n(int rp) {
  int jg = rp >> 6, c = rp & 63;
  return (c >> 4) * HID + jg * 16 + (c & 15);
}

__global__ void prep_misc(const float* __restrict__ hid0, const float* __restrict__ wout,
                          bf16* __restrict__ hb0, bf16* __restrict__ wob,
                          unsigned* __restrict__ bar)
{
  int gid = blockIdx.x * blockDim.x + threadIdx.x;
  int stride = gridDim.x * blockDim.x;
  for (int i = gid; i < BATCH * HID; i += stride) hb0[i] = __float2bfloat16(hid0[i]);
  for (int i = gid; i < NCH * HID;  i += stride) wob[i] = __float2bfloat16(wout[i]);
  if (gid < 128) bar[gid] = 0u;
}

__global__ void prep_wp(const float* __restrict__ W_ih, const float* __restrict__ W_hh,
                        bf16* __restrict__ wp)
{
  int gid = blockIdx.x * blockDim.x + threadIdx.x;
  int stride = gridDim.x * blockDim.x;
  for (int i = gid; i < NP * HID; i += stride) {
    int rp = i >> 10, k = i & 1023;
    int n = rowp_to_n(rp);
    float v = W_ih[(size_t)n * 1152 + 128 + k] + W_hh[(size_t)n * 1024 + k];
    wp[i] = __float2bfloat16(v);
  }
}

__global__ void prep_xp(const float* __restrict__ inp0, const float* __restrict__ W_ih,
                        const float* __restrict__ b_ih, const float* __restrict__ b_hh,
                        float* __restrict__ xp)
{
  int b = blockIdx.x;
  const float4* ip = (const float4*)(inp0 + b * NCH);
  for (int rp = threadIdx.x; rp < NP; rp += blockDim.x) {
    int n = rowp_to_n(rp);
    const float4* wr = (const float4*)(W_ih + (size_t)n * 1152);
    float acc = b_ih[n] + b_hh[n];
    #pragma unroll 8
    for (int q = 0; q < 32; ++q) {
      float4 a = ip[q], w = wr[q];
      acc += a.x * w.x + a.y * w.y + a.z * w.z + a.w * w.w;
    }
    xp[(size_t)b * NP + rp] = acc;
  }
}

__launch_bounds__(256, 1)
__global__ void lstm_main(const bf16* __restrict__ wp, const bf16* __restrict__ wob,
                          const float* __restrict__ xp, const float* __restrict__ cell0,
                          const float* __restrict__ bout,
                          bf16* __restrict__ hb0, bf16* __restrict__ hb1,
                          float* __restrict__ out, unsigned* __restrict__ bar)
{
  __shared__ bf16 wlds[64 * HID];        // 128 KB, xor-swizzled
  __shared__ float obuf[16][16][17];     // out tile x 16 buffered steps (+1 pad)

  const int tid  = threadIdx.x;
  const int bx   = blockIdx.x;
  const int lane = tid & 63;
  const int wv   = tid >> 6;        // wave 0..3 (rows)
  const int bm   = bx >> 6;         // batch group 0..3 (128 rows)
  const int jg   = bx & 63;         // j group (16 h-cols -> 64 gate rows)
  const int wrow = bm * 128 + wv * 32;
  const int l31  = lane & 31;
  const int lhi  = lane >> 5;
  const bool low = (l31 < 16);
  const int jj   = lane & 15;
  const int jcol = jg * 16 + jj;

  // stage fused-W slice into LDS (swizzled: byte ^= (row&7)<<4)
  {
    const char* src = (const char*)(wp + (size_t)jg * 64 * HID);
    for (int it = tid; it < 8192; it += 256) {
      int r  = it >> 7;
      int kb = (it & 127) << 4;
      bf16x8 v = *(const bf16x8*)(src + r * 2048 + kb);
      *(bf16x8*)((char*)wlds + r * 2048 + (kb ^ ((r & 7) << 4))) = v;
    }
  }

  // x_part -> registers (constant acc init; C layout: col=lane&31, row=(q&3)+8*(q>>2)+4*lhi)
  f32x16 xpA, xpB;
  #pragma unroll
  for (int q = 0; q < 16; ++q) {
    int rr = (q & 3) + ((q >> 2) << 3) + (lhi << 2);
    const float* xr = xp + (size_t)(wrow + rr) * NP + jg * 64;
    xpA[q] = xr[l31];
    xpB[q] = xr[32 + l31];
  }

  // cell state -> registers. low half-lanes own rows {0-3,8-11}+4*lhi, high own +16.
  float creg[8];
  #pragma unroll
  for (int q = 0; q < 8; ++q) {
    int rr = (q & 3) + ((q >> 2) << 3) + (lhi << 2) + (low ? 0 : 16);
    creg[q] = cell0[(size_t)(wrow + rr) * HID + jcol];
  }

  const int omt = (bx >> 3) << 4;   // out-tile batch row base (32 tiles of 16)
  const int ont = (bx & 7) << 4;    // out-tile char col base (8 tiles of 16)
  const float bo = bout[ont + jj];

  __syncthreads();

  for (int t = 0; t <= TLEN; ++t) {
    const bf16* __restrict__ hcur = (t & 1) ? hb1 : hb0;
    bf16* __restrict__ hnxt = (t & 1) ? hb0 : hb1;

    // out GEMM for step t-1 (uses h_t = hcur), wave 0 only; 16x16x1024 tile
    if (t >= 1 && wv == 0) {
      f32x4 oacc = {0.f, 0.f, 0.f, 0.f};
      const int kq = (lane >> 4) << 3;
      const bf16* ap = hcur + (size_t)(omt + jj) * HID + kq;
      const bf16* bp = wob + (size_t)(ont + jj) * HID + kq;
      #pragma unroll 8
      for (int ks = 0; ks < 32; ++ks) {
        bf16x8 av = *(const bf16x8*)(ap + ks * 32);
        bf16x8 bv = *(const bf16x8*)(bp + ks * 32);
        oacc = __builtin_amdgcn_mfma_f32_16x16x32_bf16(av, bv, oacc, 0, 0, 0);
      }
      const int slot = (t - 1) & 15;
      #pragma unroll
      for (int q = 0; q < 4; ++q)
        obuf[((lane >> 4) << 2) + q][jj][slot] = oacc[q] + bo;   // row=(l>>4)*4+q, col=jj
    }

    // flush 16 buffered output steps (coalesced 64B runs into [b][o][t] layout)
    if ((t & 15) == 0 && t >= 16) {
      __syncthreads();
      const int orow = tid >> 4, ocol = tid & 15;
      float* dst = out + ((size_t)(omt + orow) * NCH + (ont + ocol)) * TLEN + (t - 16);
      #pragma unroll
      for (int s = 0; s < 16; ++s) dst[s] = obuf[orow][ocol][s];
    }

    if (t == TLEN) break;

    // gates GEMM: [128x64] = x_part + h[128x1024] @ W'[64x1024]^T
    f32x16 accA = xpA, accB = xpB;
    {
      const bf16* ap = hcur + (size_t)(wrow + l31) * HID + (lhi << 3);
      const char* wb = (const char*)wlds;
      const int base0 = l31 * 2048;
      const int sxor  = (l31 & 7) << 4;
      const int kb4   = lhi << 4;
      #pragma unroll 8
      for (int ks = 0; ks < 64; ++ks) {
        bf16x8 av = *(const bf16x8*)(ap + ks * 16);
        const int ko = ((ks << 5) | kb4) ^ sxor;
        bf16x8 b0 = *(const bf16x8*)(wb + base0 + ko);
        bf16x8 b1 = *(const bf16x8*)(wb + base0 + 65536 + ko);
        accA = __builtin_amdgcn_mfma_f32_32x32x16_bf16(av, b0, accA, 0, 0, 0);
        accB = __builtin_amdgcn_mfma_f32_32x32x16_bf16(av, b1, accB, 0, 0, 0);
      }
    }

    // LSTM cell update. accA cols: i (l31<16) / f (l31>=16); accB: g / o.
    float s0[16], s1[16], u0[16], u1[16];
    #pragma unroll
    for (int q = 0; q < 16; ++q) {
      s0[q] = sigm(accA[q]);                       // sig(i) on low, sig(f) on high
      float a1 = accB[q];
      float sg = sigm(low ? 2.f * a1 : a1);
      s1[q] = low ? 2.f * sg - 1.f : sg;           // tanh(g) on low, sig(o) on high
    }
    #pragma unroll
    for (int q = 0; q < 16; ++q) {
      u0[q] = __shfl_xor(s0[q], 16);
      u1[q] = __shfl_xor(s1[q], 16);
    }
    #pragma unroll
    for (int q = 0; q < 8; ++q) {
      float fg  = low ? u0[q]         : s0[q + 8];
      float ig  = low ? s0[q] * s1[q] : u0[q + 8] * u1[q + 8];
      float og  = low ? u1[q]         : s1[q + 8];
      float cn  = fg * creg[q] + ig;
      creg[q] = cn;
      float hv = og * (2.f * sigm(2.f * cn) - 1.f);
      int rr = (q & 3) + ((q >> 2) << 3) + (lhi << 2) + (low ? 0 : 16);
      hnxt[(size_t)(wrow + rr) * HID + jcol] = __float2bfloat16(hv);
    }

    // grid barrier: 8-way-split arrival counters, every block polls all 8
    __syncthreads();
    if (tid == 0) {
      __threadfence();
      __hip_atomic_fetch_add(&bar[(bx & 7) << 4], 1u, __ATOMIC_RELEASE, __HIP_MEMORY_SCOPE_AGENT);
    }
    if (tid < 8) {
      const unsigned tgt = 32u * (unsigned)(t + 1);
      while (__hip_atomic_load(&bar[tid << 4], __ATOMIC_ACQUIRE, __HIP_MEMORY_SCOPE_AGENT) < tgt)
        __builtin_amdgcn_s_sleep(1);
      __threadfence();
    }
    __syncthreads();
  }
}

extern "C" void kernel_launch(void* const* d_in, const int* in_sizes, int n_in,
                              void* d_out, int out_size, void* d_ws, size_t ws_size,
                              hipStream_t stream)
{
  const float* hid0  = (const float*)d_in[0];
  const float* inp0  = (const float*)d_in[1];
  const float* cell0 = (const float*)d_in[2];
  const float* W_ih  = (const float*)d_in[3];
  const float* W_hh  = (const float*)d_in[4];
  const float* b_ih  = (const float*)d_in[5];
  const float* b_hh  = (const float*)d_in[6];
  const float* W_out = (const float*)d_in[7];
  const float* b_out = (const float*)d_in[8];
  float* out = (float*)d_out;

  char* ws = (char*)d_ws;
  bf16* wp      = (bf16*)(ws + OFF_WP);
  bf16* wob     = (bf16*)(ws + OFF_WOB);
  bf16* hb0     = (bf16*)(ws + OFF_HB0);
  bf16* hb1     = (bf16*)(ws + OFF_HB1);
  float* xp     = (float*)(ws + OFF_XP);
  unsigned* bar = (unsigned*)(ws + OFF_BAR);

  prep_misc<<<512, 256, 0, stream>>>(hid0, W_out, hb0, wob, bar);
  prep_wp<<<4096, 256, 0, stream>>>(W_ih, W_hh, wp);
  prep_xp<<<512, 256, 0, stream>>>(inp0, W_ih, b_ih, b_hh, xp);

  void* args[] = { &wp, &wob, &xp, &cell0, &b_out, &hb0, &hb1, &out, &bar };
  hipLaunchCooperativeKernel(lstm_main, dim3(256), dim3(256), args, 0u, stream);
}

// Round 6
// 9520.063 us; speedup vs baseline: 1.0500x; 1.0500x over previous
//
#include <hip/hip_runtime.h>
#include <hip/hip_bf16.h>

// LSTM decoder: B=512, H=1024, NCHAR=128, T=256.
// Round 6 = round-1 kernel (PASSED, 9996us, 39us/step, ~90% barrier cost)
// with ONE device-side change: the barrier ACQUIRE-spin (per-poll cache
// invalidate storm) is replaced by a RELAXED spin + periodic acquire fence +
// single post-spin threadfence. Release side byte-for-byte r1 (proven).
// Host side: check hipLaunchCooperativeKernel return; fall back to a regular
// launch (1 block/CU by LDS occupancy, grid == CU count) if it fails.
// NO register-resident W (KREG) -- r5 isolated that structure as the silent
// no-op breaker across r2-r5.
//  - fused W' = W_ih[:,128:] + W_hh (bf16, permuted rows) resident in LDS
//  - x_part precomputed fp32, held in registers as MFMA acc init
//  - cell state c in registers for all 256 steps
//  - h double-buffered bf16 in ws
//  - out GEMM (h@W_out^T) folded in: wave 0, 16-step obuf, r1 schedule

using bf16 = __hip_bfloat16;
typedef short bf16x8 __attribute__((ext_vector_type(8)));
typedef float f32x4  __attribute__((ext_vector_type(4)));
typedef float f32x16 __attribute__((ext_vector_type(16)));

static constexpr int BATCH = 512;
static constexpr int HID   = 1024;
static constexpr int NCH   = 128;
static constexpr int TLEN  = 256;
static constexpr int NP    = 4096;   // 4*HID

// workspace byte offsets (IDENTICAL to round 1)
static constexpr size_t OFF_WP  = 0;                                // bf16 [4096][1024] fused W, rows permuted
static constexpr size_t OFF_WOB = OFF_WP  + (size_t)NP * HID * 2;   // bf16 [128][1024]
static constexpr size_t OFF_HB0 = OFF_WOB + (size_t)NCH * HID * 2;  // bf16 h buffer 0
static constexpr size_t OFF_HB1 = OFF_HB0 + (size_t)BATCH * HID * 2;
static constexpr size_t OFF_XP  = OFF_HB1 + (size_t)BATCH * HID * 2; // f32 [512][4096] x_part permuted
static constexpr size_t OFF_BAR = OFF_XP  + (size_t)BATCH * NP * 4;  // barrier counters (8 x 64B)

__device__ __forceinline__ float sigm(float x) { return 1.f / (1.f + __expf(-x)); }

// permuted gate-row index: row' = (j>>4)*64 + gate*16 + (j&15); decode n = gate*H + j
__device__ __forceinline__ int rowp_to_n(int rp) {
  int jg = rp >> 6, c = rp & 63;
  return (c >> 4) * HID + jg * 16 + (c & 15);
}

__global__ void prep_misc(const float* __restrict__ hid0, const float* __restrict__ wout,
                          bf16* __restrict__ hb0, bf16* __restrict__ wob,
                          unsigned* __restrict__ bar)
{
  int gid = blockIdx.x * blockDim.x + threadIdx.x;
  int stride = gridDim.x * blockDim.x;
  for (int i = gid; i < BATCH * HID; i += stride) hb0[i] = __float2bfloat16(hid0[i]);
  for (int i = gid; i < NCH * HID;  i += stride) wob[i] = __float2bfloat16(wout[i]);
  if (gid < 128) bar[gid] = 0u;
}

__global__ void prep_wp(const float* __restrict__ W_ih, const float* __restrict__ W_hh,
                        bf16* __restrict__ wp)
{
  int gid = blockIdx.x * blockDim.x + threadIdx.x;
  int stride = gridDim.x * blockDim.x;
  for (int i = gid; i < NP * HID; i += stride) {
    int rp = i >> 10, k = i & 1023;
    int n = rowp_to_n(rp);
    float v = W_ih[(size_t)n * 1152 + 128 + k] + W_hh[(size_t)n * 1024 + k];
    wp[i] = __float2bfloat16(v);
  }
}

__global__ void prep_xp(const float* __restrict__ inp0, const float* __restrict__ W_ih,
                        const float* __restrict__ b_ih, const float* __restrict__ b_hh,
                        float* __restrict__ xp)
{
  int b = blockIdx.x;
  const float4* ip = (const float4*)(inp0 + b * NCH);
  for (int rp = threadIdx.x; rp < NP; rp += blockDim.x) {
    int n = rowp_to_n(rp);
    const float4* wr = (const float4*)(W_ih + (size_t)n * 1152);
    float acc = b_ih[n] + b_hh[n];
    #pragma unroll 8
    for (int q = 0; q < 32; ++q) {
      float4 a = ip[q], w = wr[q];
      acc += a.x * w.x + a.y * w.y + a.z * w.z + a.w * w.w;
    }
    xp[(size_t)b * NP + rp] = acc;
  }
}

__launch_bounds__(256, 1)
__global__ void lstm_main(const bf16* __restrict__ wp, const bf16* __restrict__ wob,
                          const float* __restrict__ xp, const float* __restrict__ cell0,
                          const float* __restrict__ bout,
                          bf16* __restrict__ hb0, bf16* __restrict__ hb1,
                          float* __restrict__ out, unsigned* __restrict__ bar)
{
  __shared__ bf16 wlds[64 * HID];        // 128 KB, xor-swizzled
  __shared__ float obuf[16][16][17];     // out tile x 16 buffered steps (+1 pad)

  const int tid  = threadIdx.x;
  const int bx   = blockIdx.x;
  const int lane = tid & 63;
  const int wv   = tid >> 6;        // wave 0..3 (rows)
  const int bm   = bx >> 6;         // batch group 0..3 (128 rows)
  const int jg   = bx & 63;         // j group (16 h-cols -> 64 gate rows)
  const int wrow = bm * 128 + wv * 32;
  const int l31  = lane & 31;
  const int lhi  = lane >> 5;
  const bool low = (l31 < 16);
  const int jj   = lane & 15;
  const int jcol = jg * 16 + jj;

  // stage fused-W slice into LDS (swizzled: byte ^= (row&7)<<4)
  {
    const char* src = (const char*)(wp + (size_t)jg * 64 * HID);
    for (int it = tid; it < 8192; it += 256) {
      int r  = it >> 7;
      int kb = (it & 127) << 4;
      bf16x8 v = *(const bf16x8*)(src + r * 2048 + kb);
      *(bf16x8*)((char*)wlds + r * 2048 + (kb ^ ((r & 7) << 4))) = v;
    }
  }

  // x_part -> registers (constant acc init; C layout: col=lane&31, row=(q&3)+8*(q>>2)+4*lhi)
  f32x16 xpA, xpB;
  #pragma unroll
  for (int q = 0; q < 16; ++q) {
    int rr = (q & 3) + ((q >> 2) << 3) + (lhi << 2);
    const float* xr = xp + (size_t)(wrow + rr) * NP + jg * 64;
    xpA[q] = xr[l31];
    xpB[q] = xr[32 + l31];
  }

  // cell state -> registers. low half-lanes own rows {0-3,8-11}+4*lhi, high own +16.
  float creg[8];
  #pragma unroll
  for (int q = 0; q < 8; ++q) {
    int rr = (q & 3) + ((q >> 2) << 3) + (lhi << 2) + (low ? 0 : 16);
    creg[q] = cell0[(size_t)(wrow + rr) * HID + jcol];
  }

  const int omt = (bx >> 3) << 4;   // out-tile batch row base (32 tiles of 16)
  const int ont = (bx & 7) << 4;    // out-tile char col base (8 tiles of 16)
  const float bo = bout[ont + jj];

  __syncthreads();

  for (int t = 0; t <= TLEN; ++t) {
    const bf16* __restrict__ hcur = (t & 1) ? hb1 : hb0;
    bf16* __restrict__ hnxt = (t & 1) ? hb0 : hb1;

    // out GEMM for step t-1 (uses h_t = hcur), wave 0 only; 16x16x1024 tile
    if (t >= 1 && wv == 0) {
      f32x4 oacc = {0.f, 0.f, 0.f, 0.f};
      const int kq = (lane >> 4) << 3;
      const bf16* ap = hcur + (size_t)(omt + jj) * HID + kq;
      const bf16* bp = wob + (size_t)(ont + jj) * HID + kq;
      #pragma unroll 8
      for (int ks = 0; ks < 32; ++ks) {
        bf16x8 av = *(const bf16x8*)(ap + ks * 32);
        bf16x8 bv = *(const bf16x8*)(bp + ks * 32);
        oacc = __builtin_amdgcn_mfma_f32_16x16x32_bf16(av, bv, oacc, 0, 0, 0);
      }
      const int slot = (t - 1) & 15;
      #pragma unroll
      for (int q = 0; q < 4; ++q)
        obuf[((lane >> 4) << 2) + q][jj][slot] = oacc[q] + bo;   // row=(l>>4)*4+q, col=jj
    }

    // flush 16 buffered output steps (coalesced 64B runs into [b][o][t] layout)
    if ((t & 15) == 0 && t >= 16) {
      __syncthreads();
      const int orow = tid >> 4, ocol = tid & 15;
      float* dst = out + ((size_t)(omt + orow) * NCH + (ont + ocol)) * TLEN + (t - 16);
      #pragma unroll
      for (int s = 0; s < 16; ++s) dst[s] = obuf[orow][ocol][s];
    }

    if (t == TLEN) break;

    // gates GEMM: [128x64] = x_part + h[128x1024] @ W'[64x1024]^T
    f32x16 accA = xpA, accB = xpB;
    {
      const bf16* ap = hcur + (size_t)(wrow + l31) * HID + (lhi << 3);
      const char* wb = (const char*)wlds;
      const int base0 = l31 * 2048;
      const int sxor  = (l31 & 7) << 4;
      const int kb4   = lhi << 4;
      #pragma unroll 8
      for (int ks = 0; ks < 64; ++ks) {
        bf16x8 av = *(const bf16x8*)(ap + ks * 16);
        const int ko = ((ks << 5) | kb4) ^ sxor;
        bf16x8 b0 = *(const bf16x8*)(wb + base0 + ko);
        bf16x8 b1 = *(const bf16x8*)(wb + base0 + 65536 + ko);
        accA = __builtin_amdgcn_mfma_f32_32x32x16_bf16(av, b0, accA, 0, 0, 0);
        accB = __builtin_amdgcn_mfma_f32_32x32x16_bf16(av, b1, accB, 0, 0, 0);
      }
    }

    // LSTM cell update. accA cols: i (l31<16) / f (l31>=16); accB: g / o.
    float s0[16], s1[16], u0[16], u1[16];
    #pragma unroll
    for (int q = 0; q < 16; ++q) {
      s0[q] = sigm(accA[q]);                       // sig(i) on low, sig(f) on high
      float a1 = accB[q];
      float sg = sigm(low ? 2.f * a1 : a1);
      s1[q] = low ? 2.f * sg - 1.f : sg;           // tanh(g) on low, sig(o) on high
    }
    #pragma unroll
    for (int q = 0; q < 16; ++q) {
      u0[q] = __shfl_xor(s0[q], 16);
      u1[q] = __shfl_xor(s1[q], 16);
    }
    #pragma unroll
    for (int q = 0; q < 8; ++q) {
      float fg  = low ? u0[q]         : s0[q + 8];
      float ig  = low ? s0[q] * s1[q] : u0[q + 8] * u1[q + 8];
      float og  = low ? u1[q]         : s1[q + 8];
      float cn  = fg * creg[q] + ig;
      creg[q] = cn;
      float hv = og * (2.f * sigm(2.f * cn) - 1.f);
      int rr = (q & 3) + ((q >> 2) << 3) + (lhi << 2) + (low ? 0 : 16);
      hnxt[(size_t)(wrow + rr) * HID + jcol] = __float2bfloat16(hv);
    }

    // grid barrier. Release side: byte-for-byte round 1 (threadfence = wbl2,
    // then RELEASE add). Spin side (THE one change): RELAXED polls of the LLC
    // counter (no per-poll invalidate), periodic acquire fence as liveness
    // hedge, single threadfence (invalidate) after the counter is seen.
    __syncthreads();
    if (tid == 0) {
      __threadfence();
      __hip_atomic_fetch_add(&bar[(bx & 7) << 4], 1u, __ATOMIC_RELEASE, __HIP_MEMORY_SCOPE_AGENT);
    }
    if (tid < 8) {
      const unsigned tgt = 32u * (unsigned)(t + 1);
      int it = 0;
      while (__hip_atomic_load(&bar[tid << 4], __ATOMIC_RELAXED, __HIP_MEMORY_SCOPE_AGENT) < tgt) {
        __builtin_amdgcn_s_sleep(2);
        if ((++it & 255) == 0) __builtin_amdgcn_fence(__ATOMIC_ACQUIRE, "agent");
      }
      __threadfence();
    }
    __syncthreads();
  }
}

extern "C" void kernel_launch(void* const* d_in, const int* in_sizes, int n_in,
                              void* d_out, int out_size, void* d_ws, size_t ws_size,
                              hipStream_t stream)
{
  const float* hid0  = (const float*)d_in[0];
  const float* inp0  = (const float*)d_in[1];
  const float* cell0 = (const float*)d_in[2];
  const float* W_ih  = (const float*)d_in[3];
  const float* W_hh  = (const float*)d_in[4];
  const float* b_ih  = (const float*)d_in[5];
  const float* b_hh  = (const float*)d_in[6];
  const float* W_out = (const float*)d_in[7];
  const float* b_out = (const float*)d_in[8];
  float* out = (float*)d_out;

  char* ws = (char*)d_ws;
  bf16* wp      = (bf16*)(ws + OFF_WP);
  bf16* wob     = (bf16*)(ws + OFF_WOB);
  bf16* hb0     = (bf16*)(ws + OFF_HB0);
  bf16* hb1     = (bf16*)(ws + OFF_HB1);
  float* xp     = (float*)(ws + OFF_XP);
  unsigned* bar = (unsigned*)(ws + OFF_BAR);

  prep_misc<<<512, 256, 0, stream>>>(hid0, W_out, hb0, wob, bar);
  prep_wp<<<4096, 256, 0, stream>>>(W_ih, W_hh, wp);
  prep_xp<<<512, 256, 0, stream>>>(inp0, W_ih, b_ih, b_hh, xp);

  void* args[] = { &wp, &wob, &xp, &cell0, &b_out, &hb0, &hb1, &out, &bar };
  hipError_t e = hipLaunchCooperativeKernel(lstm_main, dim3(256), dim3(256), args, 0u, stream);
  if (e != hipSuccess) {
    // fallback: regular launch. 1 block/CU (LDS-capped), grid == CU count ->
    // all blocks resident; the barrier protocol itself needs no coop launch.
    lstm_main<<<dim3(256), dim3(256), 0, stream>>>(wp, wob, xp, cell0, b_out,
                                                   hb0, hb1, out, bar);
  }
}

// Round 7
// 4660.212 us; speedup vs baseline: 2.1450x; 2.0428x over previous
//
#include <hip/hip_runtime.h>
#include <hip/hip_bf16.h>

// LSTM decoder: B=512, H=1024, NCHAR=128, T=256.
// Round 7 = round-6 kernel (PASSED, 9520us) with ONE change-cluster: the
// per-step grid barrier. r1/r6's shared dominant cost is 256 blocks each
// executing __threadfence() (buffer_wbl2 = full L2 dirty-writeback walk)
// every step. New protocol:
//   census (once): physical XCD id via s_getreg(HW_REG_XCC_ID), per-XCD
//     block population counted in ws; degenerate census -> all-flush fallback
//     (== r6 semantics exactly).
//   release: plain h stores -> syncthreads (compiler drains vmcnt before
//     s_barrier, so stores are in the local L2) -> relaxed per-XCD arrival
//     add; the LAST arriver per XCD does __threadfence() [wbl2 pushes ALL
//     XCD-mates' dirty h lines to LLC] -> RELEASE add to global counter.
//     => 8 wbl2/step instead of 256.
//   acquire: relaxed spin on the global counter (LLC; no per-poll inv),
//     then ONE acquire fence (buffer_inv, no wbl2) per block, syncthreads.
// Everything else byte-for-byte r6 (LDS-resident W, no KREG -- r5 isolated
// that structure as the silent no-op breaker).

using bf16 = __hip_bfloat16;
typedef short bf16x8 __attribute__((ext_vector_type(8)));
typedef float f32x4  __attribute__((ext_vector_type(4)));
typedef float f32x16 __attribute__((ext_vector_type(16)));

static constexpr int BATCH = 512;
static constexpr int HID   = 1024;
static constexpr int NCH   = 128;
static constexpr int TLEN  = 256;
static constexpr int NP    = 4096;   // 4*HID

// workspace byte offsets (bar region: 1024 u32 now; rest identical to r1/r6)
static constexpr size_t OFF_WP  = 0;                                // bf16 [4096][1024] fused W, rows permuted
static constexpr size_t OFF_WOB = OFF_WP  + (size_t)NP * HID * 2;   // bf16 [128][1024]
static constexpr size_t OFF_HB0 = OFF_WOB + (size_t)NCH * HID * 2;  // bf16 h buffer 0
static constexpr size_t OFF_HB1 = OFF_HB0 + (size_t)BATCH * HID * 2;
static constexpr size_t OFF_XP  = OFF_HB1 + (size_t)BATCH * HID * 2; // f32 [512][4096] x_part permuted
static constexpr size_t OFF_BAR = OFF_XP  + (size_t)BATCH * NP * 4;
// bar layout (u32 index, stride 32 = 128B apart):
//   [x*32]      x<8 : per-XCD population census
//   [8*32]          : census completion counter
//   [(16+x)*32] x<8 : per-XCD per-step arrival counters (monotone)
//   [24*32]         : global step counter gCnt (monotone)

__device__ __forceinline__ float sigm(float x) { return 1.f / (1.f + __expf(-x)); }

// permuted gate-row index: row' = (j>>4)*64 + gate*16 + (j&15); decode n = gate*H + j
__device__ __forceinline__ int rowp_to_n(int rp) {
  int jg = rp >> 6, c = rp & 63;
  return (c >> 4) * HID + jg * 16 + (c & 15);
}

__global__ void prep_misc(const float* __restrict__ hid0, const float* __restrict__ wout,
                          bf16* __restrict__ hb0, bf16* __restrict__ wob,
                          unsigned* __restrict__ bar)
{
  int gid = blockIdx.x * blockDim.x + threadIdx.x;
  int stride = gridDim.x * blockDim.x;
  for (int i = gid; i < BATCH * HID; i += stride) hb0[i] = __float2bfloat16(hid0[i]);
  for (int i = gid; i < NCH * HID;  i += stride) wob[i] = __float2bfloat16(wout[i]);
  if (gid < 1024) bar[gid] = 0u;
}

__global__ void prep_wp(const float* __restrict__ W_ih, const float* __restrict__ W_hh,
                        bf16* __restrict__ wp)
{
  int gid = blockIdx.x * blockDim.x + threadIdx.x;
  int stride = gridDim.x * blockDim.x;
  for (int i = gid; i < NP * HID; i += stride) {
    int rp = i >> 10, k = i & 1023;
    int n = rowp_to_n(rp);
    float v = W_ih[(size_t)n * 1152 + 128 + k] + W_hh[(size_t)n * 1024 + k];
    wp[i] = __float2bfloat16(v);
  }
}

__global__ void prep_xp(const float* __restrict__ inp0, const float* __restrict__ W_ih,
                        const float* __restrict__ b_ih, const float* __restrict__ b_hh,
                        float* __restrict__ xp)
{
  int b = blockIdx.x;
  const float4* ip = (const float4*)(inp0 + b * NCH);
  for (int rp = threadIdx.x; rp < NP; rp += blockDim.x) {
    int n = rowp_to_n(rp);
    const float4* wr = (const float4*)(W_ih + (size_t)n * 1152);
    float acc = b_ih[n] + b_hh[n];
    #pragma unroll 8
    for (int q = 0; q < 32; ++q) {
      float4 a = ip[q], w = wr[q];
      acc += a.x * w.x + a.y * w.y + a.z * w.z + a.w * w.w;
    }
    xp[(size_t)b * NP + rp] = acc;
  }
}

__launch_bounds__(256, 1)
__global__ void lstm_main(const bf16* __restrict__ wp, const bf16* __restrict__ wob,
                          const float* __restrict__ xp, const float* __restrict__ cell0,
                          const float* __restrict__ bout,
                          bf16* __restrict__ hb0, bf16* __restrict__ hb1,
                          float* __restrict__ out, unsigned* __restrict__ bar)
{
  __shared__ bf16 wlds[64 * HID];        // 128 KB, xor-swizzled
  __shared__ float obuf[16][16][17];     // out tile x 16 buffered steps (+1 pad)
  __shared__ int s_pop[8];

  const int tid  = threadIdx.x;
  const int bx   = blockIdx.x;
  const int lane = tid & 63;
  const int wv   = tid >> 6;        // wave 0..3 (rows)
  const int bm   = bx >> 6;         // batch group 0..3 (128 rows)
  const int jg   = bx & 63;         // j group (16 h-cols -> 64 gate rows)
  const int wrow = bm * 128 + wv * 32;
  const int l31  = lane & 31;
  const int lhi  = lane >> 5;
  const bool low = (l31 < 16);
  const int jj   = lane & 15;
  const int jcol = jg * 16 + jj;

  // stage fused-W slice into LDS (swizzled: byte ^= (row&7)<<4)
  {
    const char* src = (const char*)(wp + (size_t)jg * 64 * HID);
    for (int it = tid; it < 8192; it += 256) {
      int r  = it >> 7;
      int kb = (it & 127) << 4;
      bf16x8 v = *(const bf16x8*)(src + r * 2048 + kb);
      *(bf16x8*)((char*)wlds + r * 2048 + (kb ^ ((r & 7) << 4))) = v;
    }
  }

  // x_part -> registers (constant acc init; C layout: col=lane&31, row=(q&3)+8*(q>>2)+4*lhi)
  f32x16 xpA, xpB;
  #pragma unroll
  for (int q = 0; q < 16; ++q) {
    int rr = (q & 3) + ((q >> 2) << 3) + (lhi << 2);
    const float* xr = xp + (size_t)(wrow + rr) * NP + jg * 64;
    xpA[q] = xr[l31];
    xpB[q] = xr[32 + l31];
  }

  // cell state -> registers. low half-lanes own rows {0-3,8-11}+4*lhi, high own +16.
  float creg[8];
  #pragma unroll
  for (int q = 0; q < 8; ++q) {
    int rr = (q & 3) + ((q >> 2) << 3) + (lhi << 2) + (low ? 0 : 16);
    creg[q] = cell0[(size_t)(wrow + rr) * HID + jcol];
  }

  const int omt = (bx >> 3) << 4;   // out-tile batch row base (32 tiles of 16)
  const int ont = (bx & 7) << 4;    // out-tile char col base (8 tiles of 16)
  const float bo = bout[ont + jj];

  // ---- one-time census: physical XCD id + per-XCD block population
  const int myx = __builtin_amdgcn_s_getreg(6164) & 7;  // HW_REG_XCC_ID (id=20,off=0,sz=4)
  if (tid == 0) {
    __hip_atomic_fetch_add(bar + (size_t)myx * 32, 1u, __ATOMIC_RELAXED, __HIP_MEMORY_SCOPE_AGENT);
    __threadfence();   // order pop-add before census-completion add
    __hip_atomic_fetch_add(bar + (size_t)8 * 32, 1u, __ATOMIC_RELEASE, __HIP_MEMORY_SCOPE_AGENT);
    int it = 0;
    while (__hip_atomic_load(bar + (size_t)8 * 32, __ATOMIC_RELAXED, __HIP_MEMORY_SCOPE_AGENT) < 256u) {
      __builtin_amdgcn_s_sleep(2);
      if ((++it & 255) == 0) __builtin_amdgcn_fence(__ATOMIC_ACQUIRE, "agent");
    }
  }
  __syncthreads();
  if (tid < 8)
    s_pop[tid] = (int)__hip_atomic_load(bar + (size_t)tid * 32, __ATOMIC_RELAXED, __HIP_MEMORY_SCOPE_AGENT);
  __syncthreads();
  int nx = 0, tot = 0;
  #pragma unroll
  for (int i = 0; i < 8; ++i) { nx += (s_pop[i] != 0) ? 1 : 0; tot += s_pop[i]; }
  const bool elect = (nx >= 2) && (tot == 256);   // degenerate -> all-flush (r6 semantics)
  const unsigned mypop = (unsigned)s_pop[myx];
  const unsigned NF = elect ? (unsigned)nx : 256u;
  unsigned* const xcdCnt = bar + (size_t)(16 + myx) * 32;
  unsigned* const gCnt   = bar + (size_t)24 * 32;

  __syncthreads();

  for (int t = 0; t <= TLEN; ++t) {
    const bf16* __restrict__ hcur = (t & 1) ? hb1 : hb0;
    bf16* __restrict__ hnxt = (t & 1) ? hb0 : hb1;

    // out GEMM for step t-1 (uses h_t = hcur), wave 0 only; 16x16x1024 tile
    if (t >= 1 && wv == 0) {
      f32x4 oacc = {0.f, 0.f, 0.f, 0.f};
      const int kq = (lane >> 4) << 3;
      const bf16* ap = hcur + (size_t)(omt + jj) * HID + kq;
      const bf16* bp = wob + (size_t)(ont + jj) * HID + kq;
      #pragma unroll 8
      for (int ks = 0; ks < 32; ++ks) {
        bf16x8 av = *(const bf16x8*)(ap + ks * 32);
        bf16x8 bv = *(const bf16x8*)(bp + ks * 32);
        oacc = __builtin_amdgcn_mfma_f32_16x16x32_bf16(av, bv, oacc, 0, 0, 0);
      }
      const int slot = (t - 1) & 15;
      #pragma unroll
      for (int q = 0; q < 4; ++q)
        obuf[((lane >> 4) << 2) + q][jj][slot] = oacc[q] + bo;   // row=(l>>4)*4+q, col=jj
    }

    // flush 16 buffered output steps (coalesced 64B runs into [b][o][t] layout)
    if ((t & 15) == 0 && t >= 16) {
      __syncthreads();
      const int orow = tid >> 4, ocol = tid & 15;
      float* dst = out + ((size_t)(omt + orow) * NCH + (ont + ocol)) * TLEN + (t - 16);
      #pragma unroll
      for (int s = 0; s < 16; ++s) dst[s] = obuf[orow][ocol][s];
    }

    if (t == TLEN) break;

    // gates GEMM: [128x64] = x_part + h[128x1024] @ W'[64x1024]^T
    f32x16 accA = xpA, accB = xpB;
    {
      const bf16* ap = hcur + (size_t)(wrow + l31) * HID + (lhi << 3);
      const char* wb = (const char*)wlds;
      const int base0 = l31 * 2048;
      const int sxor  = (l31 & 7) << 4;
      const int kb4   = lhi << 4;
      #pragma unroll 8
      for (int ks = 0; ks < 64; ++ks) {
        bf16x8 av = *(const bf16x8*)(ap + ks * 16);
        const int ko = ((ks << 5) | kb4) ^ sxor;
        bf16x8 b0 = *(const bf16x8*)(wb + base0 + ko);
        bf16x8 b1 = *(const bf16x8*)(wb + base0 + 65536 + ko);
        accA = __builtin_amdgcn_mfma_f32_32x32x16_bf16(av, b0, accA, 0, 0, 0);
        accB = __builtin_amdgcn_mfma_f32_32x32x16_bf16(av, b1, accB, 0, 0, 0);
      }
    }

    // LSTM cell update. accA cols: i (l31<16) / f (l31>=16); accB: g / o.
    float s0[16], s1[16], u0[16], u1[16];
    #pragma unroll
    for (int q = 0; q < 16; ++q) {
      s0[q] = sigm(accA[q]);                       // sig(i) on low, sig(f) on high
      float a1 = accB[q];
      float sg = sigm(low ? 2.f * a1 : a1);
      s1[q] = low ? 2.f * sg - 1.f : sg;           // tanh(g) on low, sig(o) on high
    }
    #pragma unroll
    for (int q = 0; q < 16; ++q) {
      u0[q] = __shfl_xor(s0[q], 16);
      u1[q] = __shfl_xor(s1[q], 16);
    }
    #pragma unroll
    for (int q = 0; q < 8; ++q) {
      float fg  = low ? u0[q]         : s0[q + 8];
      float ig  = low ? s0[q] * s1[q] : u0[q + 8] * u1[q + 8];
      float og  = low ? u1[q]         : s1[q + 8];
      float cn  = fg * creg[q] + ig;
      creg[q] = cn;
      float hv = og * (2.f * sigm(2.f * cn) - 1.f);
      int rr = (q & 3) + ((q >> 2) << 3) + (lhi << 2) + (low ? 0 : 16);
      hnxt[(size_t)(wrow + rr) * HID + jcol] = __float2bfloat16(hv);
    }

    // ---- grid barrier, elected-flusher protocol ----
    // syncthreads drains vmcnt (compiler-emitted) -> all 4 waves' h stores
    // are in this XCD's L2 before tid 0 proceeds.
    __syncthreads();
    if (tid == 0) {
      unsigned old = __hip_atomic_fetch_add(xcdCnt, 1u, __ATOMIC_RELAXED, __HIP_MEMORY_SCOPE_AGENT);
      if (!elect || old == mypop * (unsigned)(t + 1) - 1u) {
        // last arriver on this XCD: all XCD-mates' h stores are in this L2.
        __threadfence();   // buffer_wbl2: push them to the LLC
        __hip_atomic_fetch_add(gCnt, 1u, __ATOMIC_RELEASE, __HIP_MEMORY_SCOPE_AGENT);
      }
      // poll: relaxed spin on the single LLC counter
      const unsigned tgt = NF * (unsigned)(t + 1);
      int it = 0;
      while (__hip_atomic_load(gCnt, __ATOMIC_RELAXED, __HIP_MEMORY_SCOPE_AGENT) < tgt) {
        __builtin_amdgcn_s_sleep(2);
        if ((++it & 255) == 0) __builtin_amdgcn_fence(__ATOMIC_ACQUIRE, "agent");
      }
    }
    // one invalidate per block (wave 0; L1 and L2 are CU/XCD-shared)
    if (tid < 64) __builtin_amdgcn_fence(__ATOMIC_ACQUIRE, "agent");
    __syncthreads();
  }
}

extern "C" void kernel_launch(void* const* d_in, const int* in_sizes, int n_in,
                              void* d_out, int out_size, void* d_ws, size_t ws_size,
                              hipStream_t stream)
{
  const float* hid0  = (const float*)d_in[0];
  const float* inp0  = (const float*)d_in[1];
  const float* cell0 = (const float*)d_in[2];
  const float* W_ih  = (const float*)d_in[3];
  const float* W_hh  = (const float*)d_in[4];
  const float* b_ih  = (const float*)d_in[5];
  const float* b_hh  = (const float*)d_in[6];
  const float* W_out = (const float*)d_in[7];
  const float* b_out = (const float*)d_in[8];
  float* out = (float*)d_out;

  char* ws = (char*)d_ws;
  bf16* wp      = (bf16*)(ws + OFF_WP);
  bf16* wob     = (bf16*)(ws + OFF_WOB);
  bf16* hb0     = (bf16*)(ws + OFF_HB0);
  bf16* hb1     = (bf16*)(ws + OFF_HB1);
  float* xp     = (float*)(ws + OFF_XP);
  unsigned* bar = (unsigned*)(ws + OFF_BAR);

  prep_misc<<<512, 256, 0, stream>>>(hid0, W_out, hb0, wob, bar);
  prep_wp<<<4096, 256, 0, stream>>>(W_ih, W_hh, wp);
  prep_xp<<<512, 256, 0, stream>>>(inp0, W_ih, b_ih, b_hh, xp);

  void* args[] = { &wp, &wob, &xp, &cell0, &b_out, &hb0, &hb1, &out, &bar };
  hipError_t e = hipLaunchCooperativeKernel(lstm_main, dim3(256), dim3(256), args, 0u, stream);
  if (e != hipSuccess) {
    // fallback: regular launch. 1 block/CU (LDS-capped), grid == CU count ->
    // all blocks resident; the barrier protocol itself needs no coop launch.
    lstm_main<<<dim3(256), dim3(256), 0, stream>>>(wp, wob, xp, cell0, b_out,
                                                   hb0, hb1, out, bar);
  }
}